// Round 7
// baseline (100.241 us; speedup 1.0000x reference)
//
#include <hip/hip_runtime.h>
#include <hip/hip_bf16.h>
#include <math.h>

// Problem constants (B=4096, D=128, T=0.5 -> 1/T = 2)
#define BB       4096
#define N2       8192          // 2B rows of z
#define DIMS     128
#define NT       64            // number of 128-row tiles per matrix side
#define NJOBS    (NT * (NT + 1) / 2)   // 2080 upper-triangle tile jobs
#define TILE     128
#define LDS_PAD  8             // bf16 pad per row: breaks 256B-stride 16B-group conflicts
#define LDS_ROWW (DIMS + LDS_PAD)  // 136 shorts = 272 B

// z rows are pre-scaled by ZSCALE so the MFMA dot directly yields
// sim * 2*log2(e), i.e. exp(sim/T) = exp2(acc). ZSCALE^2 = 2.8853900818.
#define ZSCALE   1.6986436f
// diagonal term exp(2 * |z_r|^2) ~= exp(2) — subtracted in reduce.
#define DIAG_E2  7.38905609893065f

typedef __attribute__((ext_vector_type(8))) short short8;   // 8 x bf16 (4 VGPRs)
typedef __attribute__((ext_vector_type(4))) float float4v;  // MFMA C/D

static __device__ __forceinline__ short bfb(float x) {
  __hip_bfloat16 h = __float2bfloat16(x);
  return *reinterpret_cast<short*>(&h);
}
static __device__ __forceinline__ short8 pack8(float4 a, float4 b, float inv) {
  short8 o;
  o[0] = bfb(a.x * inv); o[1] = bfb(a.y * inv);
  o[2] = bfb(a.z * inv); o[3] = bfb(a.w * inv);
  o[4] = bfb(b.x * inv); o[5] = bfb(b.y * inv);
  o[6] = bfb(b.z * inv); o[7] = bfb(b.w * inv);
  return o;
}

// ---------------------------------------------------------------------------
// Kernel 1: FULLY FUSED norm + symmetric sim-GEMM + exp2 -> private partials.
// Round-6 post-mortem: kernel boundary ~1.5 µs, norm ~4 µs, z round-trip —
// all eliminated by normalizing emb inside each tile block:
//  * A-operand: each lane normalizes the 2 rows its afrag needs IN REGISTERS.
//    The 4 quads share a row, so full-row sumsq = local 32 elems +
//    shfl_xor(16) + shfl_xor(32). No LDS, no barrier.
//  * B-operand: 2 threads/row normalize the col tile straight into the same
//    padded LDS layout the (unchanged, verified) t-loop reads.
// emb_i/emb_j (4 MiB total) stay L2-resident per XCD across the 2080 blocks.
// Block (I,J), I<J writes row-partials to P[I][J][:] and col-partials to
// P[J][I][:]; diag writes P[I][I][:]. Every cell written exactly once, no
// atomics, no fences (r1/r3 post-mortems). MFMA dot is bit-identical under
// operand transpose, so symmetry reuse is exact.
// ---------------------------------------------------------------------------
__global__ __launch_bounds__(256, 4) void simloss_fused(
    const float* __restrict__ emb_i, const float* __restrict__ emb_j,
    float* __restrict__ P, float* __restrict__ out) {
  __shared__ short lds[TILE * LDS_ROWW];   // 128 x 136 bf16 = 34816 B
  __shared__ float csum_lds[4][TILE];      // per-wave column-sum partials

  const int tid  = threadIdx.x;
  const int wave = tid >> 6;
  const int lane = tid & 63;
  const int lr   = lane & 15;          // A-row / B-col / C-col within tile
  const int quad = lane >> 4;          // k-group for A/B, row-group for C

  if (blockIdx.x == 0 && tid == 0) out[0] = 0.0f;  // reduce accumulates here

  // ---- decode flat job id -> (I, J) with I <= J over NT=64 ----
  const int j = blockIdx.x;
  int I = (int)((129.0f - sqrtf(16641.0f - 8.0f * (float)j)) * 0.5f);
  I = I < 0 ? 0 : (I > NT - 1 ? NT - 1 : I);
  while (I < NT - 1 && (I + 1) * (2 * NT - I) / 2 <= j) ++I;
  while (I > 0 && I * (2 * NT - I + 1) / 2 > j) --I;
  const int J = I + (j - I * (2 * NT - I + 1) / 2);
  const bool diag = (I == J);
  const int R0 = I * TILE;
  const int C0 = J * TILE;

  // ---- A: normalize own rows straight into afrag registers ----
  // Lane needs rows R0 + wave*32 + rt*16 + lr, elems quad*8 + k*32 + [0,8).
  // 4 quads cooperate on each row's sumsq.
  short8 afrag[2][4];
  #pragma unroll
  for (int rt = 0; rt < 2; rt++) {
    const int g = R0 + wave * 32 + rt * 16 + lr;
    const float4* bp4 = (const float4*)(g < BB
        ? emb_i + (size_t)g * DIMS
        : emb_j + (size_t)(g - BB) * DIMS);
    float4 v[8];
    float s = 0.0f;
    #pragma unroll
    for (int k = 0; k < 4; k++) {
      float4 a = bp4[quad * 2 + 8 * k];
      float4 b = bp4[quad * 2 + 8 * k + 1];
      v[2 * k] = a; v[2 * k + 1] = b;
      s += a.x * a.x + a.y * a.y + a.z * a.z + a.w * a.w;
      s += b.x * b.x + b.y * b.y + b.z * b.z + b.w * b.w;
    }
    s += __shfl_xor(s, 16, 64);
    s += __shfl_xor(s, 32, 64);
    const float inv = ZSCALE / fmaxf(sqrtf(s), 1e-12f);
    #pragma unroll
    for (int k = 0; k < 4; k++)
      afrag[rt][k] = pack8(v[2 * k], v[2 * k + 1], inv);
  }

  // ---- B: normalize col tile into LDS (2 threads per row, single pass) ----
  {
    const int row  = tid >> 1;
    const int half = tid & 1;
    const int g    = C0 + row;
    const float4* src = (const float4*)(g < BB
        ? emb_i + (size_t)g * DIMS
        : emb_j + (size_t)(g - BB) * DIMS) + half * 16;
    float4 v[16];
    float s = 0.0f;
    #pragma unroll
    for (int k = 0; k < 16; k++) {
      float4 a = src[k];
      v[k] = a;
      s += a.x * a.x + a.y * a.y + a.z * a.z + a.w * a.w;
    }
    s += __shfl_xor(s, 1, 64);   // partner thread has the other half-row
    const float inv = ZSCALE / fmaxf(sqrtf(s), 1e-12f);
    short* dst = &lds[row * LDS_ROWW + half * 64];
    #pragma unroll
    for (int w = 0; w < 8; w++)
      *(short8*)&dst[w * 8] = pack8(v[2 * w], v[2 * w + 1], inv);
  }
  __syncthreads();

  // ---- t-loop + epilogue: byte-identical to the verified r4/r6 core ----
  float rowsum[2][4];
  #pragma unroll
  for (int rt = 0; rt < 2; rt++)
    #pragma unroll
    for (int r = 0; r < 4; r++) rowsum[rt][r] = 0.0f;

  #pragma unroll 2
  for (int t = 0; t < 8; t++) {        // 8 column tiles of 16
    const short8* bp = (const short8*)&lds[(t * 16 + lr) * LDS_ROWW + quad * 8];
    short8 b0 = bp[0];
    short8 b1 = bp[4];
    short8 b2 = bp[8];
    short8 b3 = bp[12];
    float ctile = 0.0f;
    #pragma unroll
    for (int rt = 0; rt < 2; rt++) {
      float4v acc = {0.0f, 0.0f, 0.0f, 0.0f};
      acc = __builtin_amdgcn_mfma_f32_16x16x32_bf16(afrag[rt][0], b0, acc, 0, 0, 0);
      acc = __builtin_amdgcn_mfma_f32_16x16x32_bf16(afrag[rt][1], b1, acc, 0, 0, 0);
      acc = __builtin_amdgcn_mfma_f32_16x16x32_bf16(afrag[rt][2], b2, acc, 0, 0, 0);
      acc = __builtin_amdgcn_mfma_f32_16x16x32_bf16(afrag[rt][3], b3, acc, 0, 0, 0);
      // exp(sim/T) = exp2(acc) thanks to ZSCALE pre-scaling.
      #pragma unroll
      for (int r = 0; r < 4; r++) {
        float e = __builtin_amdgcn_exp2f(acc[r]);
        rowsum[rt][r] += e;
        ctile += e;
      }
    }
    if (!diag) {  // block-uniform branch
      ctile += __shfl_xor(ctile, 16, 64);
      ctile += __shfl_xor(ctile, 32, 64);
      if (quad == 0) csum_lds[wave][t * 16 + lr] = ctile;
    }
  }

  // ---- row sums: reduce across the 16 lanes of each quad, store float4 ----
  #pragma unroll
  for (int m = 1; m < 16; m <<= 1)
    #pragma unroll
    for (int rt = 0; rt < 2; rt++)
      #pragma unroll
      for (int r = 0; r < 4; r++)
        rowsum[rt][r] += __shfl_xor(rowsum[rt][r], m, 64);
  if (lr == 0) {
    float* Prow = P + ((size_t)I * NT + J) * TILE + wave * 32;
    #pragma unroll
    for (int rt = 0; rt < 2; rt++) {
      float4v v = {rowsum[rt][0], rowsum[rt][1], rowsum[rt][2], rowsum[rt][3]};
      *(float4v*)&Prow[rt * 16 + quad * 4] = v;
    }
  }

  // ---- column sums: combine 4 wave partials, coalesced store ----
  if (!diag) {
    __syncthreads();
    if (tid < TILE) {
      float s = csum_lds[0][tid] + csum_lds[1][tid] +
                csum_lds[2][tid] + csum_lds[3][tid];
      P[((size_t)J * NT + I) * TILE + tid] = s;
    }
  }
}

// ---------------------------------------------------------------------------
// Kernel 2: per-row reduction of P + fp32-exact pos recompute + log term +
// final sum. 128 blocks x 64 threads, one thread per row r:
//   denom[r] = sum_J P[r>>7][J][r&127]            (fp32, fixed order)
//   pos      = <emb_i[g], emb_j[g]> / (|emb_i[g]| |emb_j[g]|), g = r mod B
//   term     = (log(denom - e^2) - 2*pos) / N2    (double)
// Wave-reduce -> ONE float atomicAdd per block into out[0] (zeroed by sim).
// emb reads hit L2 (kept hot by the sim kernel's per-block normalization).
// ---------------------------------------------------------------------------
__global__ __launch_bounds__(64) void reduce_pos(
    const float* __restrict__ P, const float* __restrict__ emb_i,
    const float* __restrict__ emb_j, float* __restrict__ out) {
  const int tid = threadIdx.x;
  const int r   = blockIdx.x * 64 + tid;        // 128*64 = 8192 rows
  const int I   = r >> 7;
  const int rr  = r & (TILE - 1);

  const float* p = P + (size_t)I * NT * TILE + rr;
  float acc = 0.0f;
  #pragma unroll 8
  for (int J = 0; J < NT; J++) acc += p[(size_t)J * TILE];

  const int g = r & (BB - 1);
  const float4* xi = (const float4*)(emb_i + (size_t)g * DIMS);
  const float4* xj = (const float4*)(emb_j + (size_t)g * DIMS);
  float si = 0.0f, sj = 0.0f, sij = 0.0f;
  #pragma unroll
  for (int k = 0; k < 32; k++) {
    float4 a = xi[k], b = xj[k];
    si  += a.x * a.x + a.y * a.y + a.z * a.z + a.w * a.w;
    sj  += b.x * b.x + b.y * b.y + b.z * b.z + b.w * b.w;
    sij += a.x * b.x + a.y * b.y + a.z * b.z + a.w * b.w;
  }
  const float invi = 1.0f / fmaxf(sqrtf(si), 1e-12f);
  const float invj = 1.0f / fmaxf(sqrtf(sj), 1e-12f);
  const float pos  = sij * invi * invj;

  double term = (double)(logf(acc - DIAG_E2) - 2.0f * pos) / (double)N2;
  #pragma unroll
  for (int m = 32; m; m >>= 1) term += __shfl_xor(term, m, 64);
  if (tid == 0) atomicAdd(out, (float)term);
}

// ---------------------------------------------------------------------------
extern "C" void kernel_launch(void* const* d_in, const int* in_sizes, int n_in,
                              void* d_out, int out_size, void* d_ws, size_t ws_size,
                              hipStream_t stream) {
  const float* emb_i = (const float*)d_in[0];
  const float* emb_j = (const float*)d_in[1];

  // workspace layout: just the private partials tensor
  float* P = (float*)d_ws;   // 64*64*128 f32 = 2 MiB

  simloss_fused<<<NJOBS, 256, 0, stream>>>(emb_i, emb_j, P, (float*)d_out);
  reduce_pos<<<N2 / 64, 64, 0, stream>>>(P, emb_i, emb_j, (float*)d_out);
}